// Round 1
// baseline (271.658 us; speedup 1.0000x reference)
//
#include <hip/hip_runtime.h>

#define N_NODES 50000
#define N_EDGES 800000
#define D_IN 64

// ---------------- K1: xw1 = x @ w1_n  [N, 16] ----------------
__global__ __launch_bounds__(256) void k_xw1(const float* __restrict__ x,
                                             const float* __restrict__ w,
                                             float* __restrict__ out) {
    __shared__ float ws[64 * 16];
    for (int i = threadIdx.x; i < 64 * 16; i += blockDim.x) ws[i] = w[i];
    __syncthreads();
    int t = blockIdx.x * blockDim.x + threadIdx.x;
    if (t >= N_NODES * 16) return;
    int node = t >> 4, f = t & 15;
    const float* xr = x + node * D_IN;
    float acc = 0.f;
#pragma unroll
    for (int k = 0; k < D_IN; ++k) acc += xr[k] * ws[k * 16 + f];
    out[t] = acc;
}

// ---------------- K2: scatter layer-1 messages + degree ----------------
__global__ __launch_bounds__(256) void k_scatter1(const int* __restrict__ src,
                                                  const int* __restrict__ dst,
                                                  const float* __restrict__ xw,
                                                  float* __restrict__ msg,
                                                  float* __restrict__ deg) {
    long t = (long)blockIdx.x * blockDim.x + threadIdx.x;
    if (t >= (long)N_EDGES * 16) return;
    int e = (int)(t >> 4), f = (int)(t & 15);
    int s = src[e], d = dst[e];
    atomicAdd(&msg[d * 16 + f], xw[s * 16 + f]);
    if (f == 0) atomicAdd(&deg[d], 1.0f);
}

// ---------------- K3: h1 = relu(msg1/deg + x @ w1_r + b1) ----------------
__global__ __launch_bounds__(256) void k_h1(const float* __restrict__ x,
                                            const float* __restrict__ msg,
                                            const float* __restrict__ deg,
                                            const float* __restrict__ w1r,
                                            const float* __restrict__ b1,
                                            float* __restrict__ h1) {
    __shared__ float ws[64 * 16];
    __shared__ float bs[16];
    for (int i = threadIdx.x; i < 64 * 16; i += blockDim.x) ws[i] = w1r[i];
    if (threadIdx.x < 16) bs[threadIdx.x] = b1[threadIdx.x];
    __syncthreads();
    int t = blockIdx.x * blockDim.x + threadIdx.x;
    if (t >= N_NODES * 16) return;
    int node = t >> 4, f = t & 15;
    float dg = deg[node];
    dg = dg < 1.f ? 1.f : dg;
    float acc = msg[t] / dg + bs[f];
    const float* xr = x + node * D_IN;
#pragma unroll
    for (int k = 0; k < D_IN; ++k) acc += xr[k] * ws[k * 16 + f];
    h1[t] = fmaxf(acc, 0.f);
}

// ---------------- K4: hw2 = h1 @ w2_n  [N, 32] ----------------
__global__ __launch_bounds__(256) void k_hw2(const float* __restrict__ h1,
                                             const float* __restrict__ w,
                                             float* __restrict__ out) {
    __shared__ float ws[16 * 32];
    for (int i = threadIdx.x; i < 16 * 32; i += blockDim.x) ws[i] = w[i];
    __syncthreads();
    int t = blockIdx.x * blockDim.x + threadIdx.x;
    if (t >= N_NODES * 32) return;
    int node = t >> 5, f = t & 31;
    const float* hr = h1 + node * 16;
    float acc = 0.f;
#pragma unroll
    for (int k = 0; k < 16; ++k) acc += hr[k] * ws[k * 32 + f];
    out[t] = acc;
}

// ---------------- K5: scatter layer-2 messages ----------------
__global__ __launch_bounds__(256) void k_scatter2(const int* __restrict__ src,
                                                  const int* __restrict__ dst,
                                                  const float* __restrict__ hw,
                                                  float* __restrict__ msg) {
    long t = (long)blockIdx.x * blockDim.x + threadIdx.x;
    if (t >= (long)N_EDGES * 32) return;
    int e = (int)(t >> 5), f = (int)(t & 31);
    int s = src[e], d = dst[e];
    atomicAdd(&msg[d * 32 + f], hw[s * 32 + f]);
}

// ------- K6: h2 = relu(msg2/deg + h1 @ w2_r + b2); MLP head; out -------
__global__ __launch_bounds__(256) void k_final(const float* __restrict__ h1,
                                               const float* __restrict__ msg2,
                                               const float* __restrict__ deg,
                                               const float* __restrict__ w2r,
                                               const float* __restrict__ b2,
                                               const float* __restrict__ fw1,
                                               const float* __restrict__ fb1,
                                               const float* __restrict__ fw2,
                                               const float* __restrict__ fb2,
                                               const float* __restrict__ fw3,
                                               const float* __restrict__ fb3,
                                               float* __restrict__ out) {
    __shared__ float s_w2r[16 * 32];
    __shared__ float s_b2[32];
    __shared__ float s_fw1[32 * 64];
    __shared__ float s_fb1[64];
    __shared__ float s_fw2[64 * 128];
    __shared__ float s_fb2[128];
    __shared__ float s_fw3[128 * 2];
    __shared__ float s_fb3[2];

    for (int i = threadIdx.x; i < 16 * 32; i += blockDim.x) s_w2r[i] = w2r[i];
    for (int i = threadIdx.x; i < 32; i += blockDim.x) s_b2[i] = b2[i];
    for (int i = threadIdx.x; i < 32 * 64; i += blockDim.x) s_fw1[i] = fw1[i];
    for (int i = threadIdx.x; i < 64; i += blockDim.x) s_fb1[i] = fb1[i];
    for (int i = threadIdx.x; i < 64 * 128; i += blockDim.x) s_fw2[i] = fw2[i];
    for (int i = threadIdx.x; i < 128; i += blockDim.x) s_fb2[i] = fb2[i];
    for (int i = threadIdx.x; i < 128 * 2; i += blockDim.x) s_fw3[i] = fw3[i];
    for (int i = threadIdx.x; i < 2; i += blockDim.x) s_fb3[i] = fb3[i];
    __syncthreads();

    int node = blockIdx.x * blockDim.x + threadIdx.x;
    if (node >= N_NODES) return;

    float dg = deg[node];
    dg = dg < 1.f ? 1.f : dg;

    float h1l[16];
#pragma unroll
    for (int k = 0; k < 16; ++k) h1l[k] = h1[node * 16 + k];

    // h2 = relu(msg2/deg + h1 @ w2_r + b2)   [32]
    float h2[32];
#pragma unroll
    for (int f = 0; f < 32; ++f) {
        float a = msg2[node * 32 + f] / dg + s_b2[f];
#pragma unroll
        for (int k = 0; k < 16; ++k) a += h1l[k] * s_w2r[k * 32 + f];
        h2[f] = fmaxf(a, 0.f);
    }

    // h3 = relu(h2 @ fw1 + fb1)   [64]
    float h3[64];
#pragma unroll 8
    for (int j = 0; j < 64; ++j) {
        float a = s_fb1[j];
#pragma unroll
        for (int k = 0; k < 32; ++k) a += h2[k] * s_fw1[k * 64 + j];
        h3[j] = fmaxf(a, 0.f);
    }

    // h4 = relu(h3 @ fw2 + fb2) [128]; out = h4 @ fw3 + fb3 (h4 not stored)
    float o0 = s_fb3[0], o1 = s_fb3[1];
#pragma unroll 4
    for (int j = 0; j < 128; ++j) {
        float a = s_fb2[j];
#pragma unroll
        for (int k = 0; k < 64; ++k) a += h3[k] * s_fw2[k * 128 + j];
        a = fmaxf(a, 0.f);
        o0 += a * s_fw3[j * 2 + 0];
        o1 += a * s_fw3[j * 2 + 1];
    }
    out[node * 2 + 0] = o0;
    out[node * 2 + 1] = o1;
}

extern "C" void kernel_launch(void* const* d_in, const int* in_sizes, int n_in,
                              void* d_out, int out_size, void* d_ws, size_t ws_size,
                              hipStream_t stream) {
    const float* x   = (const float*)d_in[0];
    const int*   ei  = (const int*)d_in[1];
    const int*   src = ei;
    const int*   dst = ei + N_EDGES;
    const float* w1n = (const float*)d_in[2];
    const float* w1r = (const float*)d_in[3];
    const float* b1  = (const float*)d_in[4];
    const float* w2n = (const float*)d_in[5];
    const float* w2r = (const float*)d_in[6];
    const float* b2  = (const float*)d_in[7];
    const float* fw1 = (const float*)d_in[8];
    const float* fb1 = (const float*)d_in[9];
    const float* fw2 = (const float*)d_in[10];
    const float* fb2 = (const float*)d_in[11];
    const float* fw3 = (const float*)d_in[12];
    const float* fb3 = (const float*)d_in[13];
    float* out = (float*)d_out;

    float* ws   = (float*)d_ws;
    float* xw1  = ws;                  // 800000
    float* msg1 = xw1 + 800000;        // 800000
    float* h1   = msg1 + 800000;       // 800000
    float* hw2  = h1 + 800000;         // 1600000
    float* msg2 = hw2 + 1600000;       // 1600000
    float* deg  = msg2 + 1600000;      // 50000

    hipMemsetAsync(msg1, 0, 800000 * sizeof(float), stream);
    hipMemsetAsync(msg2, 0, 1600000 * sizeof(float), stream);
    hipMemsetAsync(deg, 0, 50000 * sizeof(float), stream);

    k_xw1<<<(N_NODES * 16 + 255) / 256, 256, 0, stream>>>(x, w1n, xw1);
    k_scatter1<<<(N_EDGES * 16) / 256, 256, 0, stream>>>(src, dst, xw1, msg1, deg);
    k_h1<<<(N_NODES * 16 + 255) / 256, 256, 0, stream>>>(x, msg1, deg, w1r, b1, h1);
    k_hw2<<<(N_NODES * 32 + 255) / 256, 256, 0, stream>>>(h1, w2n, hw2);
    k_scatter2<<<(N_EDGES * 32) / 256, 256, 0, stream>>>(src, dst, hw2, msg2);
    k_final<<<(N_NODES + 255) / 256, 256, 0, stream>>>(h1, msg2, deg, w2r, b2,
                                                       fw1, fb1, fw2, fb2, fw3, fb3, out);
}

// Round 2
// 230.590 us; speedup vs baseline: 1.1781x; 1.1781x over previous
//
#include <hip/hip_runtime.h>

#define N_NODES 50000
#define N_EDGES 800000
#define D_IN 64
#define SCAN_NB ((N_NODES + 255) / 256)   // 196

// ---------------- CSR build ----------------
__global__ __launch_bounds__(256) void k_count(const int* __restrict__ dst,
                                               int* __restrict__ counts) {
    int e = blockIdx.x * blockDim.x + threadIdx.x;
    if (e < N_EDGES) atomicAdd(&counts[dst[e]], 1);
}

__global__ __launch_bounds__(256) void k_scan_partial(const int* __restrict__ counts,
                                                      int* __restrict__ blockSums) {
    __shared__ int s[256];
    int i = blockIdx.x * 256 + threadIdx.x;
    s[threadIdx.x] = (i < N_NODES) ? counts[i] : 0;
    __syncthreads();
    for (int d = 128; d > 0; d >>= 1) {
        if (threadIdx.x < d) s[threadIdx.x] += s[threadIdx.x + d];
        __syncthreads();
    }
    if (threadIdx.x == 0) blockSums[blockIdx.x] = s[0];
}

__global__ __launch_bounds__(256) void k_scan_block(const int* __restrict__ blockSums,
                                                    int* __restrict__ blockOffs) {
    __shared__ int s[256];
    int t = threadIdx.x;
    s[t] = (t < SCAN_NB) ? blockSums[t] : 0;
    __syncthreads();
    if (t == 0) {
        int run = 0;
        for (int i = 0; i < SCAN_NB; ++i) { int v = s[i]; s[i] = run; run += v; }
    }
    __syncthreads();
    if (t < SCAN_NB) blockOffs[t] = s[t];
}

__global__ __launch_bounds__(256) void k_scan_final(const int* __restrict__ counts,
                                                    const int* __restrict__ blockOffs,
                                                    int* __restrict__ offs,
                                                    int* __restrict__ cursor,
                                                    float* __restrict__ deg) {
    __shared__ int s[256];
    int i = blockIdx.x * 256 + threadIdx.x;
    int v = (i < N_NODES) ? counts[i] : 0;
    s[threadIdx.x] = v;
    __syncthreads();
    for (int d = 1; d < 256; d <<= 1) {
        int t = (threadIdx.x >= d) ? s[threadIdx.x - d] : 0;
        __syncthreads();
        s[threadIdx.x] += t;
        __syncthreads();
    }
    int excl = s[threadIdx.x] - v;
    if (i < N_NODES) {
        int o = blockOffs[blockIdx.x] + excl;
        offs[i] = o;
        cursor[i] = o;
        deg[i] = (v > 1) ? (float)v : 1.0f;
    }
    if (i == 0) offs[N_NODES] = N_EDGES;
}

__global__ __launch_bounds__(256) void k_place(const int* __restrict__ src,
                                               const int* __restrict__ dst,
                                               int* __restrict__ cursor,
                                               int* __restrict__ srcSorted) {
    int e = blockIdx.x * blockDim.x + threadIdx.x;
    if (e >= N_EDGES) return;
    int pos = atomicAdd(&cursor[dst[e]], 1);
    srcSorted[pos] = src[e];
}

// ---------------- K1: xw1 = x @ w1_n  [N, 16] ----------------
__global__ __launch_bounds__(256) void k_xw1(const float* __restrict__ x,
                                             const float* __restrict__ w,
                                             float* __restrict__ out) {
    __shared__ float ws[64 * 16];
    for (int i = threadIdx.x; i < 64 * 16; i += blockDim.x) ws[i] = w[i];
    __syncthreads();
    int t = blockIdx.x * blockDim.x + threadIdx.x;
    if (t >= N_NODES * 16) return;
    int node = t >> 4, f = t & 15;
    const float* xr = x + node * D_IN;
    float acc = 0.f;
#pragma unroll
    for (int k = 0; k < D_IN; ++k) acc += xr[k] * ws[k * 16 + f];
    out[t] = acc;
}

// ------- K2: h1 = relu(gather_mean(xw1) + x @ w1_r + b1)  [N,16] -------
__global__ __launch_bounds__(256) void k_agg1h1(const float* __restrict__ x,
                                                const float* __restrict__ xw1,
                                                const int* __restrict__ offs,
                                                const int* __restrict__ srcSorted,
                                                const float* __restrict__ deg,
                                                const float* __restrict__ w1r,
                                                const float* __restrict__ b1,
                                                float* __restrict__ h1) {
    __shared__ float ws[64 * 16];
    __shared__ float bs[16];
    for (int i = threadIdx.x; i < 64 * 16; i += blockDim.x) ws[i] = w1r[i];
    if (threadIdx.x < 16) bs[threadIdx.x] = b1[threadIdx.x];
    __syncthreads();
    int t = blockIdx.x * blockDim.x + threadIdx.x;
    if (t >= N_NODES * 16) return;
    int node = t >> 4, f = t & 15;
    int beg = offs[node], end = offs[node + 1];
    float acc = 0.f;
    for (int j = beg; j < end; ++j) {
        int s = srcSorted[j];
        acc += xw1[s * 16 + f];
    }
    acc /= deg[node];
    acc += bs[f];
    const float* xr = x + node * D_IN;
#pragma unroll
    for (int k = 0; k < D_IN; ++k) acc += xr[k] * ws[k * 16 + f];
    h1[t] = fmaxf(acc, 0.f);
}

// ---------------- K3: agg2 = gather_mean(h1)  [N,16] ----------------
__global__ __launch_bounds__(256) void k_agg2(const float* __restrict__ h1,
                                              const int* __restrict__ offs,
                                              const int* __restrict__ srcSorted,
                                              const float* __restrict__ deg,
                                              float* __restrict__ agg2) {
    int t = blockIdx.x * blockDim.x + threadIdx.x;
    if (t >= N_NODES * 16) return;
    int node = t >> 4, f = t & 15;
    int beg = offs[node], end = offs[node + 1];
    float acc = 0.f;
    for (int j = beg; j < end; ++j) {
        int s = srcSorted[j];
        acc += h1[s * 16 + f];
    }
    agg2[t] = acc / deg[node];
}

// ------- K4: h2 = relu(agg2 @ w2_n + h1 @ w2_r + b2); MLP head -------
__global__ __launch_bounds__(256) void k_final(const float* __restrict__ h1,
                                               const float* __restrict__ agg2,
                                               const float* __restrict__ w2n,
                                               const float* __restrict__ w2r,
                                               const float* __restrict__ b2,
                                               const float* __restrict__ fw1,
                                               const float* __restrict__ fb1,
                                               const float* __restrict__ fw2,
                                               const float* __restrict__ fb2,
                                               const float* __restrict__ fw3,
                                               const float* __restrict__ fb3,
                                               float* __restrict__ out) {
    __shared__ float s_w2n[16 * 32];
    __shared__ float s_w2r[16 * 32];
    __shared__ float s_b2[32];
    __shared__ float s_fw1[32 * 64];
    __shared__ float s_fb1[64];
    __shared__ float s_fw2[64 * 128];
    __shared__ float s_fb2[128];
    __shared__ float s_fw3[128 * 2];
    __shared__ float s_fb3[2];

    for (int i = threadIdx.x; i < 16 * 32; i += blockDim.x) { s_w2n[i] = w2n[i]; s_w2r[i] = w2r[i]; }
    for (int i = threadIdx.x; i < 32; i += blockDim.x) s_b2[i] = b2[i];
    for (int i = threadIdx.x; i < 32 * 64; i += blockDim.x) s_fw1[i] = fw1[i];
    for (int i = threadIdx.x; i < 64; i += blockDim.x) s_fb1[i] = fb1[i];
    for (int i = threadIdx.x; i < 64 * 128; i += blockDim.x) s_fw2[i] = fw2[i];
    for (int i = threadIdx.x; i < 128; i += blockDim.x) s_fb2[i] = fb2[i];
    for (int i = threadIdx.x; i < 128 * 2; i += blockDim.x) s_fw3[i] = fw3[i];
    for (int i = threadIdx.x; i < 2; i += blockDim.x) s_fb3[i] = fb3[i];
    __syncthreads();

    int node = blockIdx.x * blockDim.x + threadIdx.x;
    if (node >= N_NODES) return;

    float h1l[16], aggm[16];
#pragma unroll
    for (int k = 0; k < 16; ++k) {
        h1l[k] = h1[node * 16 + k];
        aggm[k] = agg2[node * 16 + k];
    }

    // h2 = relu(aggm @ w2_n + h1 @ w2_r + b2)   [32]
    float h2[32];
#pragma unroll
    for (int f = 0; f < 32; ++f) {
        float a = s_b2[f];
#pragma unroll
        for (int k = 0; k < 16; ++k)
            a += aggm[k] * s_w2n[k * 32 + f] + h1l[k] * s_w2r[k * 32 + f];
        h2[f] = fmaxf(a, 0.f);
    }

    // h3 = relu(h2 @ fw1 + fb1)   [64]
    float h3[64];
#pragma unroll 8
    for (int j = 0; j < 64; ++j) {
        float a = s_fb1[j];
#pragma unroll
        for (int k = 0; k < 32; ++k) a += h2[k] * s_fw1[k * 64 + j];
        h3[j] = fmaxf(a, 0.f);
    }

    // h4 = relu(h3 @ fw2 + fb2) [128]; out = h4 @ fw3 + fb3 (h4 not stored)
    float o0 = s_fb3[0], o1 = s_fb3[1];
#pragma unroll 4
    for (int j = 0; j < 128; ++j) {
        float a = s_fb2[j];
#pragma unroll
        for (int k = 0; k < 64; ++k) a += h3[k] * s_fw2[k * 128 + j];
        a = fmaxf(a, 0.f);
        o0 += a * s_fw3[j * 2 + 0];
        o1 += a * s_fw3[j * 2 + 1];
    }
    out[node * 2 + 0] = o0;
    out[node * 2 + 1] = o1;
}

extern "C" void kernel_launch(void* const* d_in, const int* in_sizes, int n_in,
                              void* d_out, int out_size, void* d_ws, size_t ws_size,
                              hipStream_t stream) {
    const float* x   = (const float*)d_in[0];
    const int*   ei  = (const int*)d_in[1];
    const int*   src = ei;
    const int*   dst = ei + N_EDGES;
    const float* w1n = (const float*)d_in[2];
    const float* w1r = (const float*)d_in[3];
    const float* b1  = (const float*)d_in[4];
    const float* w2n = (const float*)d_in[5];
    const float* w2r = (const float*)d_in[6];
    const float* b2  = (const float*)d_in[7];
    const float* fw1 = (const float*)d_in[8];
    const float* fb1 = (const float*)d_in[9];
    const float* fw2 = (const float*)d_in[10];
    const float* fb2 = (const float*)d_in[11];
    const float* fw3 = (const float*)d_in[12];
    const float* fb3 = (const float*)d_in[13];
    float* out = (float*)d_out;

    // workspace layout (all 4-byte elements)
    int*   counts    = (int*)d_ws;                       // 50000
    int*   offs      = counts + N_NODES;                 // 50001
    int*   cursor    = offs + N_NODES + 1;               // 50000
    int*   blockSums = cursor + N_NODES;                 // 256
    int*   blockOffs = blockSums + 256;                  // 256
    int*   srcSorted = blockOffs + 256;                  // 800000
    float* deg       = (float*)(srcSorted + N_EDGES);    // 50000
    float* xw1       = deg + N_NODES;                    // 800000
    float* h1        = xw1 + 800000;                     // 800000
    float* agg2      = h1 + 800000;                      // 800000

    hipMemsetAsync(counts, 0, N_NODES * sizeof(int), stream);

    k_count<<<(N_EDGES + 255) / 256, 256, 0, stream>>>(dst, counts);
    k_scan_partial<<<SCAN_NB, 256, 0, stream>>>(counts, blockSums);
    k_scan_block<<<1, 256, 0, stream>>>(blockSums, blockOffs);
    k_scan_final<<<SCAN_NB, 256, 0, stream>>>(counts, blockOffs, offs, cursor, deg);
    k_place<<<(N_EDGES + 255) / 256, 256, 0, stream>>>(src, dst, cursor, srcSorted);

    k_xw1<<<(N_NODES * 16 + 255) / 256, 256, 0, stream>>>(x, w1n, xw1);
    k_agg1h1<<<(N_NODES * 16 + 255) / 256, 256, 0, stream>>>(x, xw1, offs, srcSorted, deg, w1r, b1, h1);
    k_agg2<<<(N_NODES * 16 + 255) / 256, 256, 0, stream>>>(h1, offs, srcSorted, deg, agg2);
    k_final<<<(N_NODES + 255) / 256, 256, 0, stream>>>(h1, agg2, w2n, w2r, b2,
                                                       fw1, fb1, fw2, fb2, fw3, fb3, out);
}

// Round 3
// 185.268 us; speedup vs baseline: 1.4663x; 1.2446x over previous
//
#include <hip/hip_runtime.h>

#define N_NODES 50000
#define N_EDGES 800000
#define D_IN 64
#define SCAN_NB ((N_NODES + 255) / 256)   // 196

// ---------------- CSR build ----------------
__global__ __launch_bounds__(256) void k_count(const int* __restrict__ dst,
                                               int* __restrict__ counts) {
    int e = blockIdx.x * blockDim.x + threadIdx.x;
    if (e < N_EDGES) atomicAdd(&counts[dst[e]], 1);
}

__global__ __launch_bounds__(256) void k_scan_partial(const int* __restrict__ counts,
                                                      int* __restrict__ blockSums) {
    __shared__ int s[256];
    int i = blockIdx.x * 256 + threadIdx.x;
    s[threadIdx.x] = (i < N_NODES) ? counts[i] : 0;
    __syncthreads();
    for (int d = 128; d > 0; d >>= 1) {
        if (threadIdx.x < d) s[threadIdx.x] += s[threadIdx.x + d];
        __syncthreads();
    }
    if (threadIdx.x == 0) blockSums[blockIdx.x] = s[0];
}

__global__ __launch_bounds__(256) void k_scan_block(const int* __restrict__ blockSums,
                                                    int* __restrict__ blockOffs) {
    __shared__ int s[256];
    int t = threadIdx.x;
    s[t] = (t < SCAN_NB) ? blockSums[t] : 0;
    __syncthreads();
    if (t == 0) {
        int run = 0;
        for (int i = 0; i < SCAN_NB; ++i) { int v = s[i]; s[i] = run; run += v; }
    }
    __syncthreads();
    if (t < SCAN_NB) blockOffs[t] = s[t];
}

__global__ __launch_bounds__(256) void k_scan_final(const int* __restrict__ counts,
                                                    const int* __restrict__ blockOffs,
                                                    int* __restrict__ offs,
                                                    int* __restrict__ cursor,
                                                    float* __restrict__ deg) {
    __shared__ int s[256];
    int i = blockIdx.x * 256 + threadIdx.x;
    int v = (i < N_NODES) ? counts[i] : 0;
    s[threadIdx.x] = v;
    __syncthreads();
    for (int d = 1; d < 256; d <<= 1) {
        int t = (threadIdx.x >= d) ? s[threadIdx.x - d] : 0;
        __syncthreads();
        s[threadIdx.x] += t;
        __syncthreads();
    }
    int excl = s[threadIdx.x] - v;
    if (i < N_NODES) {
        int o = blockOffs[blockIdx.x] + excl;
        offs[i] = o;
        cursor[i] = o;
        deg[i] = (v > 1) ? (float)v : 1.0f;
    }
    if (i == 0) offs[N_NODES] = N_EDGES;
}

__global__ __launch_bounds__(256) void k_place(const int* __restrict__ src,
                                               const int* __restrict__ dst,
                                               int* __restrict__ cursor,
                                               int* __restrict__ srcSorted) {
    int e = blockIdx.x * blockDim.x + threadIdx.x;
    if (e >= N_EDGES) return;
    int pos = atomicAdd(&cursor[dst[e]], 1);
    srcSorted[pos] = src[e];
}

// ---------------- K1: xw1 = x @ w1_n  [N, 16] ----------------
__global__ __launch_bounds__(256) void k_xw1(const float* __restrict__ x,
                                             const float* __restrict__ w,
                                             float* __restrict__ out) {
    __shared__ float ws[64 * 16];
    for (int i = threadIdx.x; i < 64 * 16; i += blockDim.x) ws[i] = w[i];
    __syncthreads();
    int t = blockIdx.x * blockDim.x + threadIdx.x;
    if (t >= N_NODES * 16) return;
    int node = t >> 4, f = t & 15;
    const float* xr = x + node * D_IN;
    float acc = 0.f;
#pragma unroll
    for (int k = 0; k < D_IN; ++k) acc += xr[k] * ws[k * 16 + f];
    out[t] = acc;
}

// ------- K2: h1 = relu(gather_mean(xw1) + x @ w1_r + b1)  [N,16] -------
__global__ __launch_bounds__(256) void k_agg1h1(const float* __restrict__ x,
                                                const float* __restrict__ xw1,
                                                const int* __restrict__ offs,
                                                const int* __restrict__ srcSorted,
                                                const float* __restrict__ deg,
                                                const float* __restrict__ w1r,
                                                const float* __restrict__ b1,
                                                float* __restrict__ h1) {
    __shared__ float ws[64 * 16];
    __shared__ float bs[16];
    for (int i = threadIdx.x; i < 64 * 16; i += blockDim.x) ws[i] = w1r[i];
    if (threadIdx.x < 16) bs[threadIdx.x] = b1[threadIdx.x];
    __syncthreads();
    int t = blockIdx.x * blockDim.x + threadIdx.x;
    if (t >= N_NODES * 16) return;
    int node = t >> 4, f = t & 15;
    int beg = offs[node], end = offs[node + 1];
    float a0 = 0.f, a1 = 0.f;
    int j = beg;
    for (; j + 4 <= end; j += 4) {
        int s0 = srcSorted[j + 0], s1 = srcSorted[j + 1];
        int s2 = srcSorted[j + 2], s3 = srcSorted[j + 3];
        float v0 = xw1[s0 * 16 + f], v1 = xw1[s1 * 16 + f];
        float v2 = xw1[s2 * 16 + f], v3 = xw1[s3 * 16 + f];
        a0 += v0 + v1;
        a1 += v2 + v3;
    }
    for (; j < end; ++j) a0 += xw1[srcSorted[j] * 16 + f];
    float acc = (a0 + a1) / deg[node] + bs[f];
    const float* xr = x + node * D_IN;
#pragma unroll
    for (int k = 0; k < D_IN; ++k) acc += xr[k] * ws[k * 16 + f];
    h1[t] = fmaxf(acc, 0.f);
}

// ---------------- K3: agg2 = gather_mean(h1)  [N,16] ----------------
__global__ __launch_bounds__(256) void k_agg2(const float* __restrict__ h1,
                                              const int* __restrict__ offs,
                                              const int* __restrict__ srcSorted,
                                              const float* __restrict__ deg,
                                              float* __restrict__ agg2) {
    int t = blockIdx.x * blockDim.x + threadIdx.x;
    if (t >= N_NODES * 16) return;
    int node = t >> 4, f = t & 15;
    int beg = offs[node], end = offs[node + 1];
    float a0 = 0.f, a1 = 0.f;
    int j = beg;
    for (; j + 4 <= end; j += 4) {
        int s0 = srcSorted[j + 0], s1 = srcSorted[j + 1];
        int s2 = srcSorted[j + 2], s3 = srcSorted[j + 3];
        float v0 = h1[s0 * 16 + f], v1 = h1[s1 * 16 + f];
        float v2 = h1[s2 * 16 + f], v3 = h1[s3 * 16 + f];
        a0 += v0 + v1;
        a1 += v2 + v3;
    }
    for (; j < end; ++j) a0 += h1[srcSorted[j] * 16 + f];
    agg2[t] = (a0 + a1) / deg[node];
}

// ------- K4 (k_head): h2=relu(agg2@w2n + h1@w2r + b2); MLP head -------
// 4 threads per node; block = 256 threads = 64 nodes.
// h2/h3 exchanged via LDS in [feat][node] layout with +1-row pad (65).
// fw2 re-laid out [q][k][32] (+8 pad per q) so q-groups hit distinct banks.
#define LD4(p) (*(const float4*)(p))
__global__ __launch_bounds__(256) void k_head(const float* __restrict__ h1,
                                              const float* __restrict__ agg2,
                                              const float* __restrict__ w2n,
                                              const float* __restrict__ w2r,
                                              const float* __restrict__ b2,
                                              const float* __restrict__ fw1,
                                              const float* __restrict__ fb1,
                                              const float* __restrict__ fw2,
                                              const float* __restrict__ fb2,
                                              const float* __restrict__ fw3,
                                              const float* __restrict__ fb3,
                                              float* __restrict__ out) {
    __shared__ __align__(16) float s_w2n[512];
    __shared__ __align__(16) float s_w2r[512];
    __shared__ __align__(16) float s_fw1[2048];
    __shared__ __align__(16) float s_fw2[4 * 2056];   // [q][k][32] + pad 8
    __shared__ __align__(16) float s_fw3[256];
    __shared__ __align__(16) float s_b2[32];
    __shared__ __align__(16) float s_fb1[64];
    __shared__ __align__(16) float s_fb2[128];
    __shared__ float s_fb3[2];
    __shared__ __align__(16) float s_h2[32 * 65];     // [f][node_local]
    __shared__ __align__(16) float s_h3[64 * 65];     // [k][node_local]

    const int tid = threadIdx.x;
    for (int i = tid; i < 512; i += 256) { s_w2n[i] = w2n[i]; s_w2r[i] = w2r[i]; }
    for (int i = tid; i < 2048; i += 256) s_fw1[i] = fw1[i];
    for (int i = tid; i < 8192; i += 256) {
        int k = i >> 7, jj = i & 127;
        s_fw2[(jj >> 5) * 2056 + k * 32 + (jj & 31)] = fw2[i];
    }
    for (int i = tid; i < 256; i += 256) s_fw3[i] = fw3[i];
    if (tid < 32) s_b2[tid] = b2[tid];
    if (tid < 64) s_fb1[tid] = fb1[tid];
    if (tid < 128) s_fb2[tid] = fb2[tid];
    if (tid < 2) s_fb3[tid] = fb3[tid];
    __syncthreads();

    const int nl = tid >> 2;          // node local 0..63
    const int q  = tid & 3;           // quarter
    const int node = blockIdx.x * 64 + nl;
    const int nodec = node < N_NODES ? node : (N_NODES - 1);

    // z = [agg2 row (16) | h1 row (16)]
    float z[32];
    {
        const float4* ag = (const float4*)(agg2 + nodec * 16);
        const float4* hr = (const float4*)(h1 + nodec * 16);
#pragma unroll
        for (int i = 0; i < 4; ++i) {
            float4 v = ag[i];
            z[4 * i + 0] = v.x; z[4 * i + 1] = v.y; z[4 * i + 2] = v.z; z[4 * i + 3] = v.w;
        }
#pragma unroll
        for (int i = 0; i < 4; ++i) {
            float4 v = hr[i];
            z[16 + 4 * i + 0] = v.x; z[16 + 4 * i + 1] = v.y; z[16 + 4 * i + 2] = v.z; z[16 + 4 * i + 3] = v.w;
        }
    }

    // ---- h2: this thread computes features f = q*8 .. q*8+7 ----
#pragma unroll
    for (int b = 0; b < 2; ++b) {
        const int f0 = q * 8 + b * 4;
        float4 acc = LD4(s_b2 + f0);
#pragma unroll
        for (int k = 0; k < 16; ++k) {
            float4 wn = LD4(s_w2n + k * 32 + f0);
            float4 wr = LD4(s_w2r + k * 32 + f0);
            float zn = z[k], zr = z[16 + k];
            acc.x += zn * wn.x + zr * wr.x;
            acc.y += zn * wn.y + zr * wr.y;
            acc.z += zn * wn.z + zr * wr.z;
            acc.w += zn * wn.w + zr * wr.w;
        }
        s_h2[(f0 + 0) * 65 + nl] = fmaxf(acc.x, 0.f);
        s_h2[(f0 + 1) * 65 + nl] = fmaxf(acc.y, 0.f);
        s_h2[(f0 + 2) * 65 + nl] = fmaxf(acc.z, 0.f);
        s_h2[(f0 + 3) * 65 + nl] = fmaxf(acc.w, 0.f);
    }
    __syncthreads();

    // ---- h3: features j = q*16 .. q*16+15 ----
    {
        const int j0 = q * 16;
        float4 a0 = LD4(s_fb1 + j0 + 0);
        float4 a1 = LD4(s_fb1 + j0 + 4);
        float4 a2 = LD4(s_fb1 + j0 + 8);
        float4 a3 = LD4(s_fb1 + j0 + 12);
#pragma unroll 4
        for (int k = 0; k < 32; ++k) {
            float hk = s_h2[k * 65 + nl];
            const float* wp = s_fw1 + k * 64 + j0;
            float4 w0 = LD4(wp + 0), w1 = LD4(wp + 4), w2 = LD4(wp + 8), w3 = LD4(wp + 12);
            a0.x += hk * w0.x; a0.y += hk * w0.y; a0.z += hk * w0.z; a0.w += hk * w0.w;
            a1.x += hk * w1.x; a1.y += hk * w1.y; a1.z += hk * w1.z; a1.w += hk * w1.w;
            a2.x += hk * w2.x; a2.y += hk * w2.y; a2.z += hk * w2.z; a2.w += hk * w2.w;
            a3.x += hk * w3.x; a3.y += hk * w3.y; a3.z += hk * w3.z; a3.w += hk * w3.w;
        }
        s_h3[(j0 + 0) * 65 + nl] = fmaxf(a0.x, 0.f);
        s_h3[(j0 + 1) * 65 + nl] = fmaxf(a0.y, 0.f);
        s_h3[(j0 + 2) * 65 + nl] = fmaxf(a0.z, 0.f);
        s_h3[(j0 + 3) * 65 + nl] = fmaxf(a0.w, 0.f);
        s_h3[(j0 + 4) * 65 + nl] = fmaxf(a1.x, 0.f);
        s_h3[(j0 + 5) * 65 + nl] = fmaxf(a1.y, 0.f);
        s_h3[(j0 + 6) * 65 + nl] = fmaxf(a1.z, 0.f);
        s_h3[(j0 + 7) * 65 + nl] = fmaxf(a1.w, 0.f);
        s_h3[(j0 + 8) * 65 + nl] = fmaxf(a2.x, 0.f);
        s_h3[(j0 + 9) * 65 + nl] = fmaxf(a2.y, 0.f);
        s_h3[(j0 + 10) * 65 + nl] = fmaxf(a2.z, 0.f);
        s_h3[(j0 + 11) * 65 + nl] = fmaxf(a2.w, 0.f);
        s_h3[(j0 + 12) * 65 + nl] = fmaxf(a3.x, 0.f);
        s_h3[(j0 + 13) * 65 + nl] = fmaxf(a3.y, 0.f);
        s_h3[(j0 + 14) * 65 + nl] = fmaxf(a3.z, 0.f);
        s_h3[(j0 + 15) * 65 + nl] = fmaxf(a3.w, 0.f);
    }
    __syncthreads();

    // ---- h4 + out: features j = q*32 .. q*32+31 ----
    {
        const int j0 = q * 32;
        float4 b0 = LD4(s_fb2 + j0 + 0),  b1 = LD4(s_fb2 + j0 + 4);
        float4 b2v = LD4(s_fb2 + j0 + 8), b3 = LD4(s_fb2 + j0 + 12);
        float4 b4 = LD4(s_fb2 + j0 + 16), b5 = LD4(s_fb2 + j0 + 20);
        float4 b6 = LD4(s_fb2 + j0 + 24), b7 = LD4(s_fb2 + j0 + 28);
        const float* wbase = s_fw2 + q * 2056;
#pragma unroll 2
        for (int k = 0; k < 64; ++k) {
            float hk = s_h3[k * 65 + nl];
            const float* wp = wbase + k * 32;
            float4 w;
            w = LD4(wp + 0);  b0.x += hk * w.x; b0.y += hk * w.y; b0.z += hk * w.z; b0.w += hk * w.w;
            w = LD4(wp + 4);  b1.x += hk * w.x; b1.y += hk * w.y; b1.z += hk * w.z; b1.w += hk * w.w;
            w = LD4(wp + 8);  b2v.x += hk * w.x; b2v.y += hk * w.y; b2v.z += hk * w.z; b2v.w += hk * w.w;
            w = LD4(wp + 12); b3.x += hk * w.x; b3.y += hk * w.y; b3.z += hk * w.z; b3.w += hk * w.w;
            w = LD4(wp + 16); b4.x += hk * w.x; b4.y += hk * w.y; b4.z += hk * w.z; b4.w += hk * w.w;
            w = LD4(wp + 20); b5.x += hk * w.x; b5.y += hk * w.y; b5.z += hk * w.z; b5.w += hk * w.w;
            w = LD4(wp + 24); b6.x += hk * w.x; b6.y += hk * w.y; b6.z += hk * w.z; b6.w += hk * w.w;
            w = LD4(wp + 28); b7.x += hk * w.x; b7.y += hk * w.y; b7.z += hk * w.z; b7.w += hk * w.w;
        }
        float o0 = 0.f, o1 = 0.f;
        float4 f1, f2;
#define OUTSTEP(bb, boff)                                                    \
        f1 = LD4(s_fw3 + (j0 + boff) * 2);                                   \
        f2 = LD4(s_fw3 + (j0 + boff) * 2 + 4);                               \
        { float r0 = fmaxf(bb.x, 0.f), r1 = fmaxf(bb.y, 0.f),                \
                r2 = fmaxf(bb.z, 0.f), r3 = fmaxf(bb.w, 0.f);                \
          o0 += r0 * f1.x + r1 * f1.z + r2 * f2.x + r3 * f2.z;               \
          o1 += r0 * f1.y + r1 * f1.w + r2 * f2.y + r3 * f2.w; }
        OUTSTEP(b0, 0)  OUTSTEP(b1, 4)  OUTSTEP(b2v, 8)  OUTSTEP(b3, 12)
        OUTSTEP(b4, 16) OUTSTEP(b5, 20) OUTSTEP(b6, 24)  OUTSTEP(b7, 28)
#undef OUTSTEP
        // reduce across the 4 q-lanes (adjacent lanes)
        o0 += __shfl_xor(o0, 1); o0 += __shfl_xor(o0, 2);
        o1 += __shfl_xor(o1, 1); o1 += __shfl_xor(o1, 2);
        if (q == 0 && node < N_NODES) {
            float2 r; r.x = o0 + s_fb3[0]; r.y = o1 + s_fb3[1];
            *(float2*)(out + node * 2) = r;
        }
    }
}

extern "C" void kernel_launch(void* const* d_in, const int* in_sizes, int n_in,
                              void* d_out, int out_size, void* d_ws, size_t ws_size,
                              hipStream_t stream) {
    const float* x   = (const float*)d_in[0];
    const int*   ei  = (const int*)d_in[1];
    const int*   src = ei;
    const int*   dst = ei + N_EDGES;
    const float* w1n = (const float*)d_in[2];
    const float* w1r = (const float*)d_in[3];
    const float* b1  = (const float*)d_in[4];
    const float* w2n = (const float*)d_in[5];
    const float* w2r = (const float*)d_in[6];
    const float* b2  = (const float*)d_in[7];
    const float* fw1 = (const float*)d_in[8];
    const float* fb1 = (const float*)d_in[9];
    const float* fw2 = (const float*)d_in[10];
    const float* fb2 = (const float*)d_in[11];
    const float* fw3 = (const float*)d_in[12];
    const float* fb3 = (const float*)d_in[13];
    float* out = (float*)d_out;

    // workspace layout (all 4-byte elements)
    int*   counts    = (int*)d_ws;                       // 50000
    int*   offs      = counts + N_NODES;                 // 50001
    int*   cursor    = offs + N_NODES + 1;               // 50000
    int*   blockSums = cursor + N_NODES;                 // 256
    int*   blockOffs = blockSums + 256;                  // 256
    int*   srcSorted = blockOffs + 256;                  // 800000
    float* deg       = (float*)(srcSorted + N_EDGES);    // 50000
    float* xw1       = deg + N_NODES;                    // 800000
    float* h1        = xw1 + 800000;                     // 800000
    float* agg2      = h1 + 800000;                      // 800000

    hipMemsetAsync(counts, 0, N_NODES * sizeof(int), stream);

    k_count<<<(N_EDGES + 255) / 256, 256, 0, stream>>>(dst, counts);
    k_scan_partial<<<SCAN_NB, 256, 0, stream>>>(counts, blockSums);
    k_scan_block<<<1, 256, 0, stream>>>(blockSums, blockOffs);
    k_scan_final<<<SCAN_NB, 256, 0, stream>>>(counts, blockOffs, offs, cursor, deg);
    k_place<<<(N_EDGES + 255) / 256, 256, 0, stream>>>(src, dst, cursor, srcSorted);

    k_xw1<<<(N_NODES * 16 + 255) / 256, 256, 0, stream>>>(x, w1n, xw1);
    k_agg1h1<<<(N_NODES * 16 + 255) / 256, 256, 0, stream>>>(x, xw1, offs, srcSorted, deg, w1r, b1, h1);
    k_agg2<<<(N_NODES * 16 + 255) / 256, 256, 0, stream>>>(h1, offs, srcSorted, deg, agg2);
    k_head<<<(N_NODES + 63) / 64, 256, 0, stream>>>(h1, agg2, w2n, w2r, b2,
                                                    fw1, fb1, fw2, fb2, fw3, fb3, out);
}

// Round 4
// 156.012 us; speedup vs baseline: 1.7413x; 1.1875x over previous
//
#include <hip/hip_runtime.h>

#define N_NODES 50000
#define N_EDGES 800000
#define D_IN 64
#define LD4(p) (*(const float4*)(p))

// ---- K1: fused edge-chain build + node linear projections ----
// grid = 800000 threads exactly. Edge role: e = t. Node role: (t>>4, t&15).
// N_EDGES == N_NODES*16 == 800000, so both roles cover every thread.
__global__ __launch_bounds__(256) void k_link_lin1(
        const int* __restrict__ src, const int* __restrict__ dst,
        int* __restrict__ head, int2* __restrict__ next_src,
        const float* __restrict__ x,
        const float* __restrict__ w1n, const float* __restrict__ w1r,
        const float* __restrict__ b1,
        float* __restrict__ xw1n, float* __restrict__ xr1b) {
    __shared__ float wn[64 * 16];
    __shared__ float wr[64 * 16];
    __shared__ float bs[16];
    for (int i = threadIdx.x; i < 64 * 16; i += 256) { wn[i] = w1n[i]; wr[i] = w1r[i]; }
    if (threadIdx.x < 16) bs[threadIdx.x] = b1[threadIdx.x];

    const int t = blockIdx.x * 256 + threadIdx.x;   // always < 800000

    // edge part: LIFO chain insert (coalesced 8B write, no write-amp)
    {
        int d = dst[t], s = src[t];
        int old = atomicExch(&head[d], t);
        next_src[t] = make_int2(old, s);
    }
    __syncthreads();

    // node part: xw1n = x@w1n ; xr1b = x@w1r + b1
    {
        const int node = t >> 4, f = t & 15;
        const float* xr = x + node * D_IN;
        float an = 0.f, ar = bs[f];
#pragma unroll
        for (int k = 0; k < D_IN; ++k) {
            float xv = xr[k];
            an += xv * wn[k * 16 + f];
            ar += xv * wr[k * 16 + f];
        }
        xw1n[t] = an;
        xr1b[t] = ar;
    }
}

// ---- K2: h1 = relu(mean_nbrs(xw1n) + xr1b) via chain chase ----
__global__ __launch_bounds__(256) void k_agg1(
        const float* __restrict__ xw1n, const float* __restrict__ xr1b,
        const int* __restrict__ head, const int2* __restrict__ next_src,
        float* __restrict__ h1) {
    const int t = blockIdx.x * 256 + threadIdx.x;
    if (t >= N_NODES * 16) return;
    const int node = t >> 4, f = t & 15;
    int e = head[node];
    float a = 0.f;
    int cnt = 0;
    while (e >= 0) {
        int2 ns = next_src[e];          // broadcast across the 16-lane group
        a += xw1n[ns.y * 16 + f];       // 64B coalesced row read
        ++cnt;
        e = ns.x;
    }
    float inv = cnt > 0 ? 1.f / (float)cnt : 1.f;
    h1[t] = fmaxf(a * inv + xr1b[t], 0.f);
}

// ---- K3 (k_head): chase h1-chain (agg2) + SAGE2 + MLP head, fused ----
// 4 threads per node; block = 256 threads = 64 nodes.
__global__ __launch_bounds__(256) void k_head(const float* __restrict__ h1,
                                              const int* __restrict__ head,
                                              const int2* __restrict__ next_src,
                                              const float* __restrict__ w2n,
                                              const float* __restrict__ w2r,
                                              const float* __restrict__ b2,
                                              const float* __restrict__ fw1,
                                              const float* __restrict__ fb1,
                                              const float* __restrict__ fw2,
                                              const float* __restrict__ fb2,
                                              const float* __restrict__ fw3,
                                              const float* __restrict__ fb3,
                                              float* __restrict__ out) {
    __shared__ __align__(16) float s_w2n[512];
    __shared__ __align__(16) float s_w2r[512];
    __shared__ __align__(16) float s_fw1[2048];
    __shared__ __align__(16) float s_fw2[4 * 2056];   // [q][k][32] + pad 8
    __shared__ __align__(16) float s_fw3[256];
    __shared__ __align__(16) float s_b2[32];
    __shared__ __align__(16) float s_fb1[64];
    __shared__ __align__(16) float s_fb2[128];
    __shared__ float s_fb3[2];
    __shared__ __align__(16) float s_agg[16 * 65];    // [f][node_local]
    __shared__ __align__(16) float s_h2[32 * 65];     // [f][node_local]
    __shared__ __align__(16) float s_h3[64 * 65];     // [k][node_local]

    const int tid = threadIdx.x;
    for (int i = tid; i < 512; i += 256) { s_w2n[i] = w2n[i]; s_w2r[i] = w2r[i]; }
    for (int i = tid; i < 2048; i += 256) s_fw1[i] = fw1[i];
    for (int i = tid; i < 8192; i += 256) {
        int k = i >> 7, jj = i & 127;
        s_fw2[(jj >> 5) * 2056 + k * 32 + (jj & 31)] = fw2[i];
    }
    for (int i = tid; i < 256; i += 256) s_fw3[i] = fw3[i];
    if (tid < 32) s_b2[tid] = b2[tid];
    if (tid < 64) s_fb1[tid] = fb1[tid];
    if (tid < 128) s_fb2[tid] = fb2[tid];
    if (tid < 2) s_fb3[tid] = fb3[tid];
    __syncthreads();

    const int nl = tid >> 2;          // node local 0..63
    const int q  = tid & 3;           // quarter
    const int node = blockIdx.x * 64 + nl;
    const int nodec = node < N_NODES ? node : (N_NODES - 1);

    // ---- chase h1-chain: lane q accumulates features q*4..q*4+3 ----
    {
        float4 agg = make_float4(0.f, 0.f, 0.f, 0.f);
        int e = head[nodec];
        int cnt = 0;
        while (e >= 0) {
            int2 ns = next_src[e];                       // broadcast in 4-lane group
            float4 v = LD4(h1 + ns.y * 16 + q * 4);      // 4 lanes x 16B = 64B
            agg.x += v.x; agg.y += v.y; agg.z += v.z; agg.w += v.w;
            ++cnt;
            e = ns.x;
        }
        float inv = cnt > 0 ? 1.f / (float)cnt : 1.f;
        s_agg[(q * 4 + 0) * 65 + nl] = agg.x * inv;
        s_agg[(q * 4 + 1) * 65 + nl] = agg.y * inv;
        s_agg[(q * 4 + 2) * 65 + nl] = agg.z * inv;
        s_agg[(q * 4 + 3) * 65 + nl] = agg.w * inv;
    }
    __syncthreads();

    // z = [agg2 row (16) | h1 row (16)]
    float z[32];
#pragma unroll
    for (int k = 0; k < 16; ++k) z[k] = s_agg[k * 65 + nl];
    {
        const float4* hr = (const float4*)(h1 + nodec * 16);
#pragma unroll
        for (int i = 0; i < 4; ++i) {
            float4 v = hr[i];
            z[16 + 4 * i + 0] = v.x; z[16 + 4 * i + 1] = v.y;
            z[16 + 4 * i + 2] = v.z; z[16 + 4 * i + 3] = v.w;
        }
    }

    // ---- h2: this thread computes features f = q*8 .. q*8+7 ----
#pragma unroll
    for (int b = 0; b < 2; ++b) {
        const int f0 = q * 8 + b * 4;
        float4 acc = LD4(s_b2 + f0);
#pragma unroll
        for (int k = 0; k < 16; ++k) {
            float4 wn = LD4(s_w2n + k * 32 + f0);
            float4 wr = LD4(s_w2r + k * 32 + f0);
            float zn = z[k], zr = z[16 + k];
            acc.x += zn * wn.x + zr * wr.x;
            acc.y += zn * wn.y + zr * wr.y;
            acc.z += zn * wn.z + zr * wr.z;
            acc.w += zn * wn.w + zr * wr.w;
        }
        s_h2[(f0 + 0) * 65 + nl] = fmaxf(acc.x, 0.f);
        s_h2[(f0 + 1) * 65 + nl] = fmaxf(acc.y, 0.f);
        s_h2[(f0 + 2) * 65 + nl] = fmaxf(acc.z, 0.f);
        s_h2[(f0 + 3) * 65 + nl] = fmaxf(acc.w, 0.f);
    }
    __syncthreads();

    // ---- h3: features j = q*16 .. q*16+15 ----
    {
        const int j0 = q * 16;
        float4 a0 = LD4(s_fb1 + j0 + 0);
        float4 a1 = LD4(s_fb1 + j0 + 4);
        float4 a2 = LD4(s_fb1 + j0 + 8);
        float4 a3 = LD4(s_fb1 + j0 + 12);
#pragma unroll 4
        for (int k = 0; k < 32; ++k) {
            float hk = s_h2[k * 65 + nl];
            const float* wp = s_fw1 + k * 64 + j0;
            float4 w0 = LD4(wp + 0), w1 = LD4(wp + 4), w2 = LD4(wp + 8), w3 = LD4(wp + 12);
            a0.x += hk * w0.x; a0.y += hk * w0.y; a0.z += hk * w0.z; a0.w += hk * w0.w;
            a1.x += hk * w1.x; a1.y += hk * w1.y; a1.z += hk * w1.z; a1.w += hk * w1.w;
            a2.x += hk * w2.x; a2.y += hk * w2.y; a2.z += hk * w2.z; a2.w += hk * w2.w;
            a3.x += hk * w3.x; a3.y += hk * w3.y; a3.z += hk * w3.z; a3.w += hk * w3.w;
        }
        s_h3[(j0 + 0) * 65 + nl] = fmaxf(a0.x, 0.f);
        s_h3[(j0 + 1) * 65 + nl] = fmaxf(a0.y, 0.f);
        s_h3[(j0 + 2) * 65 + nl] = fmaxf(a0.z, 0.f);
        s_h3[(j0 + 3) * 65 + nl] = fmaxf(a0.w, 0.f);
        s_h3[(j0 + 4) * 65 + nl] = fmaxf(a1.x, 0.f);
        s_h3[(j0 + 5) * 65 + nl] = fmaxf(a1.y, 0.f);
        s_h3[(j0 + 6) * 65 + nl] = fmaxf(a1.z, 0.f);
        s_h3[(j0 + 7) * 65 + nl] = fmaxf(a1.w, 0.f);
        s_h3[(j0 + 8) * 65 + nl] = fmaxf(a2.x, 0.f);
        s_h3[(j0 + 9) * 65 + nl] = fmaxf(a2.y, 0.f);
        s_h3[(j0 + 10) * 65 + nl] = fmaxf(a2.z, 0.f);
        s_h3[(j0 + 11) * 65 + nl] = fmaxf(a2.w, 0.f);
        s_h3[(j0 + 12) * 65 + nl] = fmaxf(a3.x, 0.f);
        s_h3[(j0 + 13) * 65 + nl] = fmaxf(a3.y, 0.f);
        s_h3[(j0 + 14) * 65 + nl] = fmaxf(a3.z, 0.f);
        s_h3[(j0 + 15) * 65 + nl] = fmaxf(a3.w, 0.f);
    }
    __syncthreads();

    // ---- h4 + out: features j = q*32 .. q*32+31 ----
    {
        const int j0 = q * 32;
        float4 b0 = LD4(s_fb2 + j0 + 0),  b1 = LD4(s_fb2 + j0 + 4);
        float4 b2v = LD4(s_fb2 + j0 + 8), b3 = LD4(s_fb2 + j0 + 12);
        float4 b4 = LD4(s_fb2 + j0 + 16), b5 = LD4(s_fb2 + j0 + 20);
        float4 b6 = LD4(s_fb2 + j0 + 24), b7 = LD4(s_fb2 + j0 + 28);
        const float* wbase = s_fw2 + q * 2056;
#pragma unroll 2
        for (int k = 0; k < 64; ++k) {
            float hk = s_h3[k * 65 + nl];
            const float* wp = wbase + k * 32;
            float4 w;
            w = LD4(wp + 0);  b0.x += hk * w.x; b0.y += hk * w.y; b0.z += hk * w.z; b0.w += hk * w.w;
            w = LD4(wp + 4);  b1.x += hk * w.x; b1.y += hk * w.y; b1.z += hk * w.z; b1.w += hk * w.w;
            w = LD4(wp + 8);  b2v.x += hk * w.x; b2v.y += hk * w.y; b2v.z += hk * w.z; b2v.w += hk * w.w;
            w = LD4(wp + 12); b3.x += hk * w.x; b3.y += hk * w.y; b3.z += hk * w.z; b3.w += hk * w.w;
            w = LD4(wp + 16); b4.x += hk * w.x; b4.y += hk * w.y; b4.z += hk * w.z; b4.w += hk * w.w;
            w = LD4(wp + 20); b5.x += hk * w.x; b5.y += hk * w.y; b5.z += hk * w.z; b5.w += hk * w.w;
            w = LD4(wp + 24); b6.x += hk * w.x; b6.y += hk * w.y; b6.z += hk * w.z; b6.w += hk * w.w;
            w = LD4(wp + 28); b7.x += hk * w.x; b7.y += hk * w.y; b7.z += hk * w.z; b7.w += hk * w.w;
        }
        float o0 = 0.f, o1 = 0.f;
        float4 f1, f2;
#define OUTSTEP(bb, boff)                                                    \
        f1 = LD4(s_fw3 + (j0 + boff) * 2);                                   \
        f2 = LD4(s_fw3 + (j0 + boff) * 2 + 4);                               \
        { float r0 = fmaxf(bb.x, 0.f), r1 = fmaxf(bb.y, 0.f),                \
                r2 = fmaxf(bb.z, 0.f), r3 = fmaxf(bb.w, 0.f);                \
          o0 += r0 * f1.x + r1 * f1.z + r2 * f2.x + r3 * f2.z;               \
          o1 += r0 * f1.y + r1 * f1.w + r2 * f2.y + r3 * f2.w; }
        OUTSTEP(b0, 0)  OUTSTEP(b1, 4)  OUTSTEP(b2v, 8)  OUTSTEP(b3, 12)
        OUTSTEP(b4, 16) OUTSTEP(b5, 20) OUTSTEP(b6, 24)  OUTSTEP(b7, 28)
#undef OUTSTEP
        // reduce across the 4 q-lanes (adjacent lanes)
        o0 += __shfl_xor(o0, 1); o0 += __shfl_xor(o0, 2);
        o1 += __shfl_xor(o1, 1); o1 += __shfl_xor(o1, 2);
        if (q == 0 && node < N_NODES) {
            float2 r; r.x = o0 + s_fb3[0]; r.y = o1 + s_fb3[1];
            *(float2*)(out + node * 2) = r;
        }
    }
}

extern "C" void kernel_launch(void* const* d_in, const int* in_sizes, int n_in,
                              void* d_out, int out_size, void* d_ws, size_t ws_size,
                              hipStream_t stream) {
    const float* x   = (const float*)d_in[0];
    const int*   ei  = (const int*)d_in[1];
    const int*   src = ei;
    const int*   dst = ei + N_EDGES;
    const float* w1n = (const float*)d_in[2];
    const float* w1r = (const float*)d_in[3];
    const float* b1  = (const float*)d_in[4];
    const float* w2n = (const float*)d_in[5];
    const float* w2r = (const float*)d_in[6];
    const float* b2  = (const float*)d_in[7];
    const float* fw1 = (const float*)d_in[8];
    const float* fb1 = (const float*)d_in[9];
    const float* fw2 = (const float*)d_in[10];
    const float* fb2 = (const float*)d_in[11];
    const float* fw3 = (const float*)d_in[12];
    const float* fb3 = (const float*)d_in[13];
    float* out = (float*)d_out;

    // workspace layout (d_ws assumed >=16B aligned)
    int2*  next_src = (int2*)d_ws;                        // 800000 int2 (6.4MB)
    int*   head     = (int*)(next_src + N_EDGES);         // 50000
    float* xw1n     = (float*)(head + N_NODES);           // 800000
    float* xr1b     = xw1n + 800000;                      // 800000
    float* h1       = xr1b + 800000;                      // 800000

    hipMemsetAsync(head, 0xFF, N_NODES * sizeof(int), stream);   // head = -1

    k_link_lin1<<<N_EDGES / 256, 256, 0, stream>>>(src, dst, head, next_src,
                                                   x, w1n, w1r, b1, xw1n, xr1b);
    k_agg1<<<(N_NODES * 16 + 255) / 256, 256, 0, stream>>>(xw1n, xr1b, head, next_src, h1);
    k_head<<<(N_NODES + 63) / 64, 256, 0, stream>>>(h1, head, next_src, w2n, w2r, b2,
                                                    fw1, fb1, fw2, fb2, fw3, fb3, out);
}

// Round 5
// 155.374 us; speedup vs baseline: 1.7484x; 1.0041x over previous
//
#include <hip/hip_runtime.h>
#include <hip/hip_fp16.h>

#define N_NODES 50000
#define N_EDGES 800000
#define D_IN 64
#define MAXD 64
#define LD4(p) (*(const float4*)(p))

// ---- K1: fill padded adjacency (atomic-consolidated writes) + node linears ----
// 800000 threads: edge role e=t; node role (t>>4, t&15). 800000 == 50000*16.
__global__ __launch_bounds__(256) void k_fill_lin1(
        const int* __restrict__ src, const int* __restrict__ dst,
        int* __restrict__ cnt, int* __restrict__ nbr,
        const float* __restrict__ x,
        const float* __restrict__ w1n, const float* __restrict__ w1r,
        const float* __restrict__ b1,
        __half* __restrict__ xw1n, __half* __restrict__ xr1b) {
    __shared__ float wn[1024], wr[1024], bs[16];
    for (int i = threadIdx.x; i < 1024; i += 256) { wn[i] = w1n[i]; wr[i] = w1r[i]; }
    if (threadIdx.x < 16) bs[threadIdx.x] = b1[threadIdx.x];

    const int t = blockIdx.x * 256 + threadIdx.x;   // < 800000 always

    // edge part: slot = rank within dst; atomicExch so the line is dirtied at
    // the device coherence point once (avoids per-XCD partial-line writebacks)
    {
        int d = dst[t], s = src[t];
        int r = atomicAdd(&cnt[d], 1);
        if (r < MAXD) atomicExch(&nbr[(d << 6) + r], s);
    }
    __syncthreads();

    // node part: xw1n = x@w1n ; xr1b = x@w1r + b1  (fp16 storage, f32 math)
    {
        const int node = t >> 4, f = t & 15;
        const float* xr = x + node * D_IN;
        float an = 0.f, ar = bs[f];
#pragma unroll
        for (int k = 0; k < D_IN; ++k) {
            float xv = xr[k];
            an += xv * wn[k * 16 + f];
            ar += xv * wr[k * 16 + f];
        }
        xw1n[t] = __float2half(an);
        xr1b[t] = __float2half(ar);
    }
}

// ---- K2: h1 = relu(mean_nbrs(xw1n) + xr1b), padded-adjacency gather ----
__global__ __launch_bounds__(256) void k_agg1(
        const __half* __restrict__ xw1n, const __half* __restrict__ xr1b,
        const int* __restrict__ cnt, const int* __restrict__ nbr,
        __half* __restrict__ h1) {
    const int t = blockIdx.x * 256 + threadIdx.x;
    if (t >= N_NODES * 16) return;
    const int node = t >> 4, f = t & 15;
    int c = cnt[node];
    float inv = c > 0 ? 1.f / (float)c : 1.f;
    int cc = c > MAXD ? MAXD : c;
    const int* np = nbr + (node << 6);
    float a0 = 0.f, a1 = 0.f;
    int j = 0;
    for (; j + 2 <= cc; j += 2) {
        int s0 = np[j], s1 = np[j + 1];
        a0 += __half2float(xw1n[(s0 << 4) + f]);
        a1 += __half2float(xw1n[(s1 << 4) + f]);
    }
    if (j < cc) a0 += __half2float(xw1n[(np[j] << 4) + f]);
    h1[t] = __float2half(fmaxf((a0 + a1) * inv + __half2float(xr1b[t]), 0.f));
}

// ---- K3 (k_head): inline agg2 gather + SAGE2 + MLP head ----
// 4 lanes per node, 64 nodes per 256-thread block. Intermediates exchanged
// via quad-__shfl (no s_h2/s_h3 LDS tiles): LDS 47KB -> 3 blocks/CU.
__global__ __launch_bounds__(256) void k_head(
        const __half* __restrict__ h1,
        const int* __restrict__ cnt, const int* __restrict__ nbr,
        const float* __restrict__ w2n, const float* __restrict__ w2r,
        const float* __restrict__ b2,
        const float* __restrict__ fw1, const float* __restrict__ fb1,
        const float* __restrict__ fw2, const float* __restrict__ fb2,
        const float* __restrict__ fw3, const float* __restrict__ fb3,
        float* __restrict__ out) {
    __shared__ __align__(16) float s_w2n[512];
    __shared__ __align__(16) float s_w2r[512];
    __shared__ __align__(16) float s_fw1[2048];
    __shared__ __align__(16) float s_fw2[4 * 2056];   // [q][k][32] + pad 8
    __shared__ __align__(16) float s_fw3[256];
    __shared__ __align__(16) float s_b2[32];
    __shared__ __align__(16) float s_fb1[64];
    __shared__ __align__(16) float s_fb2[128];
    __shared__ float s_fb3[2];

    const int tid = threadIdx.x;
    for (int i = tid; i < 512; i += 256) { s_w2n[i] = w2n[i]; s_w2r[i] = w2r[i]; }
    for (int i = tid; i < 2048; i += 256) s_fw1[i] = fw1[i];
    for (int i = tid; i < 8192; i += 256) {
        int k = i >> 7, jj = i & 127;
        s_fw2[(jj >> 5) * 2056 + k * 32 + (jj & 31)] = fw2[i];
    }
    s_fw3[tid] = fw3[tid & 255];
    if (tid < 32) s_b2[tid] = b2[tid];
    if (tid < 64) s_fb1[tid] = fb1[tid];
    if (tid < 128) s_fb2[tid] = fb2[tid];
    if (tid < 2) s_fb3[tid] = fb3[tid];
    __syncthreads();

    const int nl = tid >> 2;             // node local 0..63
    const int q  = tid & 3;              // quarter lane
    const int node = blockIdx.x * 64 + nl;
    const int nodec = node < N_NODES ? node : (N_NODES - 1);
    const int qbase = (tid & 63) & ~3;   // quad base lane in wave

    // ---- agg2 gather: lane q accumulates h1 features q*4..q*4+3 ----
    float za[4];
    {
        int c = cnt[nodec];
        float inv = c > 0 ? 1.f / (float)c : 1.f;
        int cc = c > MAXD ? MAXD : c;
        const int* np = nbr + (nodec << 6);
        float a0 = 0.f, a1 = 0.f, a2 = 0.f, a3 = 0.f;
        for (int j = 0; j < cc; ++j) {
            int s = np[j];                                   // quad broadcast
            const __half2* hp = (const __half2*)(h1 + (s << 4) + (q << 2));
            float2 v0 = __half22float2(hp[0]);
            float2 v1 = __half22float2(hp[1]);
            a0 += v0.x; a1 += v0.y; a2 += v1.x; a3 += v1.y;
        }
        za[0] = a0 * inv; za[1] = a1 * inv; za[2] = a2 * inv; za[3] = a3 * inv;
    }
    // own h1 slice
    float zh[4];
    {
        const __half2* hp = (const __half2*)(h1 + (nodec << 4) + (q << 2));
        float2 v0 = __half22float2(hp[0]), v1 = __half22float2(hp[1]);
        zh[0] = v0.x; zh[1] = v0.y; zh[2] = v1.x; zh[3] = v1.y;
    }

    // ---- h2 = relu(agg@w2n + h1@w2r + b2): f-slice 8 (f0 = q*8) ----
    float h2r[8];
    {
        const int f0 = q * 8;
        float4 accA = LD4(s_b2 + f0), accB = LD4(s_b2 + f0 + 4);
#pragma unroll
        for (int k = 0; k < 16; ++k) {
            int sl = qbase + (k >> 2);
            float zn = __shfl(za[k & 3], sl);
            float zr = __shfl(zh[k & 3], sl);
            float4 wnA = LD4(s_w2n + k * 32 + f0), wnB = LD4(s_w2n + k * 32 + f0 + 4);
            float4 wrA = LD4(s_w2r + k * 32 + f0), wrB = LD4(s_w2r + k * 32 + f0 + 4);
            accA.x += zn * wnA.x + zr * wrA.x;
            accA.y += zn * wnA.y + zr * wrA.y;
            accA.z += zn * wnA.z + zr * wrA.z;
            accA.w += zn * wnA.w + zr * wrA.w;
            accB.x += zn * wnB.x + zr * wrB.x;
            accB.y += zn * wnB.y + zr * wrB.y;
            accB.z += zn * wnB.z + zr * wrB.z;
            accB.w += zn * wnB.w + zr * wrB.w;
        }
        h2r[0] = fmaxf(accA.x, 0.f); h2r[1] = fmaxf(accA.y, 0.f);
        h2r[2] = fmaxf(accA.z, 0.f); h2r[3] = fmaxf(accA.w, 0.f);
        h2r[4] = fmaxf(accB.x, 0.f); h2r[5] = fmaxf(accB.y, 0.f);
        h2r[6] = fmaxf(accB.z, 0.f); h2r[7] = fmaxf(accB.w, 0.f);
    }

    // ---- h3 = relu(h2@fw1 + fb1): j-slice 16 (j0 = q*16) ----
    float h3r[16];
    {
        const int j0 = q * 16;
        float4 a0 = LD4(s_fb1 + j0 + 0), a1 = LD4(s_fb1 + j0 + 4);
        float4 a2 = LD4(s_fb1 + j0 + 8), a3 = LD4(s_fb1 + j0 + 12);
#pragma unroll
        for (int k = 0; k < 32; ++k) {
            float hk = __shfl(h2r[k & 7], qbase + (k >> 3));
            const float* wp = s_fw1 + k * 64 + j0;
            float4 w0 = LD4(wp + 0), w1 = LD4(wp + 4), w2 = LD4(wp + 8), w3 = LD4(wp + 12);
            a0.x += hk * w0.x; a0.y += hk * w0.y; a0.z += hk * w0.z; a0.w += hk * w0.w;
            a1.x += hk * w1.x; a1.y += hk * w1.y; a1.z += hk * w1.z; a1.w += hk * w1.w;
            a2.x += hk * w2.x; a2.y += hk * w2.y; a2.z += hk * w2.z; a2.w += hk * w2.w;
            a3.x += hk * w3.x; a3.y += hk * w3.y; a3.z += hk * w3.z; a3.w += hk * w3.w;
        }
        h3r[0]  = fmaxf(a0.x, 0.f); h3r[1]  = fmaxf(a0.y, 0.f);
        h3r[2]  = fmaxf(a0.z, 0.f); h3r[3]  = fmaxf(a0.w, 0.f);
        h3r[4]  = fmaxf(a1.x, 0.f); h3r[5]  = fmaxf(a1.y, 0.f);
        h3r[6]  = fmaxf(a1.z, 0.f); h3r[7]  = fmaxf(a1.w, 0.f);
        h3r[8]  = fmaxf(a2.x, 0.f); h3r[9]  = fmaxf(a2.y, 0.f);
        h3r[10] = fmaxf(a2.z, 0.f); h3r[11] = fmaxf(a2.w, 0.f);
        h3r[12] = fmaxf(a3.x, 0.f); h3r[13] = fmaxf(a3.y, 0.f);
        h3r[14] = fmaxf(a3.z, 0.f); h3r[15] = fmaxf(a3.w, 0.f);
    }

    // ---- h4 = relu(h3@fw2 + fb2), out = h4@fw3 + fb3: j-slice 32 ----
    {
        const int j0 = q * 32;
        float4 b0 = LD4(s_fb2 + j0 + 0),  b1v = LD4(s_fb2 + j0 + 4);
        float4 b2v = LD4(s_fb2 + j0 + 8), b3v = LD4(s_fb2 + j0 + 12);
        float4 b4v = LD4(s_fb2 + j0 + 16), b5v = LD4(s_fb2 + j0 + 20);
        float4 b6v = LD4(s_fb2 + j0 + 24), b7v = LD4(s_fb2 + j0 + 28);
        const float* wbase = s_fw2 + q * 2056;
#pragma unroll
        for (int k = 0; k < 64; ++k) {
            float hk = __shfl(h3r[k & 15], qbase + (k >> 4));
            const float* wp = wbase + k * 32;
            float4 w;
            w = LD4(wp + 0);  b0.x += hk * w.x; b0.y += hk * w.y; b0.z += hk * w.z; b0.w += hk * w.w;
            w = LD4(wp + 4);  b1v.x += hk * w.x; b1v.y += hk * w.y; b1v.z += hk * w.z; b1v.w += hk * w.w;
            w = LD4(wp + 8);  b2v.x += hk * w.x; b2v.y += hk * w.y; b2v.z += hk * w.z; b2v.w += hk * w.w;
            w = LD4(wp + 12); b3v.x += hk * w.x; b3v.y += hk * w.y; b3v.z += hk * w.z; b3v.w += hk * w.w;
            w = LD4(wp + 16); b4v.x += hk * w.x; b4v.y += hk * w.y; b4v.z += hk * w.z; b4v.w += hk * w.w;
            w = LD4(wp + 20); b5v.x += hk * w.x; b5v.y += hk * w.y; b5v.z += hk * w.z; b5v.w += hk * w.w;
            w = LD4(wp + 24); b6v.x += hk * w.x; b6v.y += hk * w.y; b6v.z += hk * w.z; b6v.w += hk * w.w;
            w = LD4(wp + 28); b7v.x += hk * w.x; b7v.y += hk * w.y; b7v.z += hk * w.z; b7v.w += hk * w.w;
        }
        float o0 = 0.f, o1 = 0.f;
        float4 f1, f2;
#define OUTSTEP(bb, boff)                                                    \
        f1 = LD4(s_fw3 + (j0 + boff) * 2);                                   \
        f2 = LD4(s_fw3 + (j0 + boff) * 2 + 4);                               \
        { float r0 = fmaxf(bb.x, 0.f), r1 = fmaxf(bb.y, 0.f),                \
                r2 = fmaxf(bb.z, 0.f), r3 = fmaxf(bb.w, 0.f);                \
          o0 += r0 * f1.x + r1 * f1.z + r2 * f2.x + r3 * f2.z;               \
          o1 += r0 * f1.y + r1 * f1.w + r2 * f2.y + r3 * f2.w; }
        OUTSTEP(b0, 0)   OUTSTEP(b1v, 4)  OUTSTEP(b2v, 8)   OUTSTEP(b3v, 12)
        OUTSTEP(b4v, 16) OUTSTEP(b5v, 20) OUTSTEP(b6v, 24)  OUTSTEP(b7v, 28)
#undef OUTSTEP
        o0 += __shfl_xor(o0, 1); o0 += __shfl_xor(o0, 2);
        o1 += __shfl_xor(o1, 1); o1 += __shfl_xor(o1, 2);
        if (q == 0 && node < N_NODES) {
            float2 r; r.x = o0 + s_fb3[0]; r.y = o1 + s_fb3[1];
            *(float2*)(out + node * 2) = r;
        }
    }
}

extern "C" void kernel_launch(void* const* d_in, const int* in_sizes, int n_in,
                              void* d_out, int out_size, void* d_ws, size_t ws_size,
                              hipStream_t stream) {
    const float* x   = (const float*)d_in[0];
    const int*   ei  = (const int*)d_in[1];
    const int*   src = ei;
    const int*   dst = ei + N_EDGES;
    const float* w1n = (const float*)d_in[2];
    const float* w1r = (const float*)d_in[3];
    const float* b1  = (const float*)d_in[4];
    const float* w2n = (const float*)d_in[5];
    const float* w2r = (const float*)d_in[6];
    const float* b2  = (const float*)d_in[7];
    const float* fw1 = (const float*)d_in[8];
    const float* fb1 = (const float*)d_in[9];
    const float* fw2 = (const float*)d_in[10];
    const float* fb2 = (const float*)d_in[11];
    const float* fw3 = (const float*)d_in[12];
    const float* fb3 = (const float*)d_in[13];
    float* out = (float*)d_out;

    // workspace layout: 12.8MB + 0.2MB + 3x1.6MB = 17.8MB
    int*    nbr  = (int*)d_ws;                      // 50000*64 ints
    int*    cnt  = nbr + N_NODES * MAXD;            // 50000 ints
    __half* xw1n = (__half*)(cnt + N_NODES);        // 800000 halves
    __half* xr1b = xw1n + 800000;                   // 800000
    __half* h1   = xr1b + 800000;                   // 800000

    hipMemsetAsync(cnt, 0, N_NODES * sizeof(int), stream);

    k_fill_lin1<<<N_EDGES / 256, 256, 0, stream>>>(src, dst, cnt, nbr,
                                                   x, w1n, w1r, b1, xw1n, xr1b);
    k_agg1<<<(N_NODES * 16 + 255) / 256, 256, 0, stream>>>(xw1n, xr1b, cnt, nbr, h1);
    k_head<<<(N_NODES + 63) / 64, 256, 0, stream>>>(h1, cnt, nbr, w2n, w2r, b2,
                                                    fw1, fb1, fw2, fb2, fw3, fb3, out);
}